// Round 5
// baseline (725.968 us; speedup 1.0000x reference)
//
#include <hip/hip_runtime.h>

// ---------------------------------------------------------------------------
// SlotAttention on MI355X (gfx950) — single persistent kernel, software grid
// barrier. 512 blocks x 256 threads, __launch_bounds__(256,2) => 2 blocks/CU
// guaranteed by resources (VGPR<=256, LDS 57.5KBx2<=160KB) -> spin barrier safe.
// Round-2 lesson: ACQUIRE polling at agent scope = cache ops per poll.
// Round-3 lesson: single-line relaxed polling serializes at coherence point.
// Round-4 lesson: barriers now ~2us; kernel is LATENCY-bound at 1 wave/SIMD
// (VALUBusy 3%, hbm 6% peak). This round: double occupancy (2 blocks/CU).
// Phases (7 barriers):
//   P0: weight->bf16 + slots init + LN(inputs)->bf16
//   P1: kv GEMM (1024 tiles, 2/block) + init q (blocks 0..15)
//   3x { ATTN (512 blocks: 32 b x 16 chunks of 64 tokens) ; ROW (16 blocks,
//        16 slot-rows each: combine+GRU+LN+MLP+residual+LN+next-q) }
// MFMA fragment layouts per learn_hip m89/m97 (ref-verified):
//   A/B operand: idx = lane&15 (m or n), k = (lane>>4)*8 + j
//   C/D:         col = lane&15, row = (lane>>4)*4 + reg
// kv-GEMM LDS tiles XOR-swizzled (slot ^= (row>>1)&3): read conflicts 8->2 way.
// ---------------------------------------------------------------------------

typedef __attribute__((ext_vector_type(8))) __bf16 bf16x8;
typedef __attribute__((ext_vector_type(4))) float  f32x4;

#define MFMA16(a, b, c) __builtin_amdgcn_mfma_f32_16x16x32_bf16((a), (b), (c), 0, 0, 0)

static __device__ __forceinline__ unsigned short f2bf(float f) {
    unsigned int x = __float_as_uint(f);
    x = (x + 0x7fffu + ((x >> 16) & 1u)) >> 16;   // RN-even
    return (unsigned short)x;
}

struct Params {
    const float *inputs, *noise, *mu, *ls;
    const float *Wq, *Wk, *Wv, *wih, *whh, *bih, *bhh, *w1, *b1, *w2, *b2;
    const float *ln_in_g, *ln_in_b, *ln_s_g, *ln_s_b, *ln_ff_g, *ln_ff_b;
    float* out;
    unsigned*  bar;   // barrier lines (memset to 0 before launch), 64-uint stride
    unsigned short *x_bf, *kvW_bf, *Wq_bf, *wih_bf, *whh_bf, *w1_bf, *w2_bf;
    float *kv, *slots, *q, *upart, *rspart;
};

union Smem {
    struct { unsigned short As[128 * 32], Bs[128 * 32]; } g;          // 16 KB (kv gemm)
    struct { float q[8][260]; float sc[8][68]; } at;                  // 10.4 KB (attn)
    struct {
        unsigned short u[16][264];     // combine result / ln_s (bf16, pad +8)
        unsigned short h[16][264];     // slots_prev bf16
        unsigned short ff[16][264];    // LN_ff out bf16
        unsigned short h1[16][520];    // half of MLP hidden (512 + 8 pad)
        float          s[16][260];     // slots f32 (prev -> mid -> new)
    } row;                                                             // 57.25 KB
};

// ---- hierarchical software grid barrier ------------------------------------
// bar layout (uints, 64-uint = 256B stride): cnt[g]=bar+g*64 (g=0..7, 64 blocks
// per group), gcnt=bar+8*64, rel[g]=bar+(9+g)*64. Counters monotonic across
// phases (ph=1..7): group-last sees my == 64*ph-1, global master gm == 8*ph-1.
static __device__ __forceinline__ void gridbar(unsigned* bar, unsigned ph) {
    __syncthreads();
    if (threadIdx.x == 0) {
        const unsigned g = blockIdx.x & 7;
        unsigned my = __hip_atomic_fetch_add(bar + g * 64, 1u,
                                             __ATOMIC_ACQ_REL, __HIP_MEMORY_SCOPE_AGENT);
        if (my == ph * 64u - 1u) {                      // last of my group
            unsigned gm = __hip_atomic_fetch_add(bar + 8 * 64, 1u,
                                                 __ATOMIC_ACQ_REL, __HIP_MEMORY_SCOPE_AGENT);
            if (gm == ph * 8u - 1u) {                   // global master: publish
                #pragma unroll
                for (int k = 0; k < 8; ++k)
                    __hip_atomic_store(bar + (9 + k) * 64, ph,
                                       __ATOMIC_RELEASE, __HIP_MEMORY_SCOPE_AGENT);
            }
        }
        while (__hip_atomic_load(bar + (9 + g) * 64,
                                 __ATOMIC_RELAXED, __HIP_MEMORY_SCOPE_AGENT) < ph)
            __builtin_amdgcn_s_sleep(8);
        __builtin_amdgcn_fence(__ATOMIC_ACQUIRE, "agent");
    }
    __syncthreads();
}

// ---------------- P0b: LN(inputs) rows -> bf16, one row per wave ------------
static __device__ void ln_input(const Params& p) {
    const int wid  = (blockIdx.x * 256 + threadIdx.x) >> 6;   // 0..2047
    const int lane = threadIdx.x & 63;
    const float g0 = p.ln_in_g[lane * 4 + 0], g1 = p.ln_in_g[lane * 4 + 1];
    const float g2 = p.ln_in_g[lane * 4 + 2], g3 = p.ln_in_g[lane * 4 + 3];
    const float b0 = p.ln_in_b[lane * 4 + 0], b1 = p.ln_in_b[lane * 4 + 1];
    const float b2 = p.ln_in_b[lane * 4 + 2], b3 = p.ln_in_b[lane * 4 + 3];
    #pragma unroll 2
    for (int row = wid; row < 32768; row += 2048) {
        float4 v = *(const float4*)(p.inputs + (size_t)row * 256 + lane * 4);
        float s  = v.x + v.y + v.z + v.w;
        float ss = v.x * v.x + v.y * v.y + v.z * v.z + v.w * v.w;
        #pragma unroll
        for (int o = 1; o < 64; o <<= 1) { s += __shfl_xor(s, o); ss += __shfl_xor(ss, o); }
        float mean = s * (1.f / 256.f);
        float var  = ss * (1.f / 256.f) - mean * mean;
        float rstd = rsqrtf(var + 1e-5f);
        ushort4 o4;
        o4.x = f2bf((v.x - mean) * rstd * g0 + b0);
        o4.y = f2bf((v.y - mean) * rstd * g1 + b1);
        o4.z = f2bf((v.z - mean) * rstd * g2 + b2);
        o4.w = f2bf((v.w - mean) * rstd * g3 + b3);
        *(ushort4*)(p.x_bf + (size_t)row * 256 + lane * 4) = o4;
    }
}

// ---------------- P1a: kv = x_ln @ [Wk;Wv]^T, one 128x128 tile --------------
static __device__ void kv_tile(const Params& p, Smem& sm, int tile) {
    const int m0 = (tile >> 2) * 128, n0 = (tile & 3) * 128;
    const int t = threadIdx.x, wave = t >> 6, lane = t & 63;
    const int qr = (wave >> 1) * 64, qc = (wave & 1) * 64;
    const int lr = lane & 15, lq = lane >> 4;
    f32x4 acc[4][4] = {};
    const int sr = t >> 2, sl = t & 3, gk = sl * 8;
    const int wsl0 = (sl ^ ((sr >> 1) & 3)) * 8;               // swizzled slots
    const int wsl1 = (sl ^ (((sr + 64) >> 1) & 3)) * 8;
    for (int k0 = 0; k0 < 256; k0 += 32) {
        __syncthreads();
        uint4 a0 = *(const uint4*)(p.x_bf   + (size_t)(m0 + sr)      * 256 + k0 + gk);
        uint4 a1 = *(const uint4*)(p.x_bf   + (size_t)(m0 + sr + 64) * 256 + k0 + gk);
        uint4 b0 = *(const uint4*)(p.kvW_bf + (size_t)(n0 + sr)      * 256 + k0 + gk);
        uint4 b1 = *(const uint4*)(p.kvW_bf + (size_t)(n0 + sr + 64) * 256 + k0 + gk);
        *(uint4*)(sm.g.As + sr * 32 + wsl0) = a0;
        *(uint4*)(sm.g.As + (sr + 64) * 32 + wsl1) = a1;
        *(uint4*)(sm.g.Bs + sr * 32 + wsl0) = b0;
        *(uint4*)(sm.g.Bs + (sr + 64) * 32 + wsl1) = b1;
        __syncthreads();
        bf16x8 af[4], bv[4];
        #pragma unroll
        for (int i = 0; i < 4; i++) {
            const int ra = qr + i * 16 + lr;
            af[i] = *(const bf16x8*)(sm.g.As + ra * 32 + ((lq ^ ((ra >> 1) & 3)) * 8));
        }
        #pragma unroll
        for (int i = 0; i < 4; i++) {
            const int rb = qc + i * 16 + lr;
            bv[i] = *(const bf16x8*)(sm.g.Bs + rb * 32 + ((lq ^ ((rb >> 1) & 3)) * 8));
        }
        #pragma unroll
        for (int i = 0; i < 4; i++)
            #pragma unroll
            for (int j = 0; j < 4; j++)
                acc[i][j] = MFMA16(af[i], bv[j], acc[i][j]);
    }
    #pragma unroll
    for (int i = 0; i < 4; i++)
        #pragma unroll
        for (int j = 0; j < 4; j++) {
            const int col = n0 + qc + j * 16 + lr;
            #pragma unroll
            for (int r = 0; r < 4; r++) {
                const int rw = m0 + qr + i * 16 + lq * 4 + r;
                p.kv[(size_t)rw * 512 + col] = acc[i][j][r];
            }
        }
}

// ---------------- q = ln_s(16 rows in sm.row.u) @ Wq^T ----------------------
static __device__ void qgemm(const Params& p, Smem& sm, int r0) {
    const int t = threadIdx.x, w = t >> 6, lane = t & 63;
    const int lr = lane & 15, lq = lane >> 4;
    f32x4 acc[4] = {};
    for (int k0 = 0; k0 < 256; k0 += 32) {
        bf16x8 a = *(const bf16x8*)&sm.row.u[lr][k0 + lq * 8];
        #pragma unroll
        for (int j = 0; j < 4; ++j) {
            bf16x8 bv = *(const bf16x8*)(p.Wq_bf + (size_t)(w * 64 + j * 16 + lr) * 256 + k0 + lq * 8);
            acc[j] = MFMA16(a, bv, acc[j]);
        }
    }
    #pragma unroll
    for (int j = 0; j < 4; ++j)
        #pragma unroll
        for (int r = 0; r < 4; ++r)
            p.q[(size_t)(r0 + lq * 4 + r) * 256 + w * 64 + j * 16 + lr] = acc[j][r];
}

// ---------------- P1b: initial LN(slots) -> q (blocks 0..15) ----------------
static __device__ void init_q(const Params& p, Smem& sm, int bid) {
    const int t = threadIdx.x;
    const int r0 = bid * 16;
    const int row16 = t >> 4, sub = t & 15;
    float vals[16]; float s = 0.f, ss = 0.f;
    #pragma unroll
    for (int k = 0; k < 16; k += 4) {
        float4 v = *(const float4*)(p.slots + (size_t)(r0 + row16) * 256 + sub * 16 + k);
        vals[k] = v.x; vals[k + 1] = v.y; vals[k + 2] = v.z; vals[k + 3] = v.w;
        s += v.x + v.y + v.z + v.w;
        ss += v.x * v.x + v.y * v.y + v.z * v.z + v.w * v.w;
    }
    #pragma unroll
    for (int m = 1; m < 16; m <<= 1) { s += __shfl_xor(s, m); ss += __shfl_xor(ss, m); }
    const float mean = s * (1.f / 256.f);
    const float var  = ss * (1.f / 256.f) - mean * mean;
    const float rstd = rsqrtf(var + 1e-5f);
    #pragma unroll
    for (int k = 0; k < 16; ++k) {
        const int c = sub * 16 + k;
        sm.row.u[row16][c] = f2bf((vals[k] - mean) * rstd * p.ln_s_g[c] + p.ln_s_b[c]);
    }
    __syncthreads();
    qgemm(p, sm, r0);
}

// ---------------- ATTN: dots + softmax(slots) + EPS + partial sums ----------
// 512 blocks: b = bid>>4 (32 batches), chunk = bid&15 (16 chunks of 64 tokens).
static __device__ void attn_phase(const Params& p, Smem& sm, int bid) {
    const int t = threadIdx.x;
    const int b = bid >> 4, chunk = bid & 15, j0 = chunk * 64;
    {   // q rows for this batch (8 x 256 f32)
        const int i = t >> 5, c0 = (t & 31) * 8;
        const float* qr = p.q + (size_t)(b * 8 + i) * 256 + c0;
        *(float4*)&sm.at.q[i][c0]     = *(const float4*)(qr);
        *(float4*)&sm.at.q[i][c0 + 4] = *(const float4*)(qr + 4);
    }
    __syncthreads();
    {   // dots for 64 tokens x 8 slots
        const int i = t & 7, jj = t >> 3;          // jj: 0..31
        const float4* qrow = (const float4*)&sm.at.q[i][0];
        #pragma unroll 1
        for (int g = 0; g < 2; ++g) {
            const int jl = g * 32 + jj;
            const float4* krow = (const float4*)(p.kv + ((size_t)b * 1024 + j0 + jl) * 512);
            float a0 = 0, a1 = 0, a2 = 0, a3 = 0;
            #pragma unroll 8
            for (int dd = 0; dd < 64; ++dd) {
                float4 qv = qrow[dd], kk = krow[dd];
                a0 += qv.x * kk.x; a1 += qv.y * kk.y; a2 += qv.z * kk.z; a3 += qv.w * kk.w;
            }
            sm.at.sc[i][jl] = (a0 + a1 + a2 + a3) * 0.0625f;   // SCALE
        }
    }
    __syncthreads();
    if (t < 64) {   // softmax over slots per token + EPS
        float v[8], m = -1e30f;
        #pragma unroll
        for (int ii = 0; ii < 8; ++ii) { v[ii] = sm.at.sc[ii][t]; m = fmaxf(m, v[ii]); }
        float s = 0.f;
        #pragma unroll
        for (int ii = 0; ii < 8; ++ii) { v[ii] = __expf(v[ii] - m); s += v[ii]; }
        const float inv = 1.f / s;
        #pragma unroll
        for (int ii = 0; ii < 8; ++ii) sm.at.sc[ii][t] = v[ii] * inv + 1e-8f;
    }
    __syncthreads();
    if (t < 8) {    // per-slot row-sum partial over this 64-token chunk
        float s = 0.f;
        for (int jl = 0; jl < 64; ++jl) s += sm.at.sc[t][jl];
        p.rspart[((size_t)b * 16 + chunk) * 8 + t] = s;
    }
    {   // partial updates: acc[i] += w[i][j] * v[j][d], d = t
        float acc[8] = {};
        const float* vbase = p.kv + ((size_t)b * 1024 + j0) * 512 + 256 + t;
        #pragma unroll 8
        for (int jl = 0; jl < 64; ++jl) {
            const float vv = vbase[(size_t)jl * 512];
            #pragma unroll
            for (int ii = 0; ii < 8; ++ii) acc[ii] += sm.at.sc[ii][jl] * vv;
        }
        float* up = p.upart + (((size_t)b * 16 + chunk) * 8) * 256 + t;
        #pragma unroll
        for (int ii = 0; ii < 8; ++ii) up[(size_t)ii * 256] = acc[ii];
    }
}

// ---------------- ROW: combine -> gates -> GRU -> LN -> MLP -> out -> q -----
static __device__ void row_phase(const Params& p, Smem& sm, int bid, int it) {
    const int t = threadIdx.x;
    const int r0 = bid * 16;
    const int lane = t & 63, w = t >> 6;
    const int lr = lane & 15, lq = lane >> 4;
    const int row16 = t >> 4, sub = t & 15;
    const int c0 = w * 64;

    // 1. slots f32 -> s LDS (+ bf16 h LDS); combine upart/rspart -> u LDS bf16
    #pragma unroll
    for (int k = 0; k < 16; k += 4) {
        float4 v = *(const float4*)(p.slots + (size_t)(r0 + row16) * 256 + sub * 16 + k);
        *(float4*)&sm.row.s[row16][sub * 16 + k] = v;
        sm.row.h[row16][sub * 16 + k]     = f2bf(v.x);
        sm.row.h[row16][sub * 16 + k + 1] = f2bf(v.y);
        sm.row.h[row16][sub * 16 + k + 2] = f2bf(v.z);
        sm.row.h[row16][sub * 16 + k + 3] = f2bf(v.w);
    }
    {
        const int grow = r0 + row16, bb = grow >> 3, ii = grow & 7;
        float rs = 0.f;
        #pragma unroll
        for (int c = 0; c < 16; ++c) rs += p.rspart[((size_t)bb * 16 + c) * 8 + ii];
        const float inv = 1.f / rs;
        float uac[16] = {};
        #pragma unroll
        for (int c = 0; c < 16; ++c) {
            const float* up = p.upart + (((size_t)bb * 16 + c) * 8 + ii) * 256 + sub * 16;
            #pragma unroll
            for (int k = 0; k < 16; k += 4) {
                float4 v = *(const float4*)(up + k);
                uac[k] += v.x; uac[k + 1] += v.y; uac[k + 2] += v.z; uac[k + 3] += v.w;
            }
        }
        #pragma unroll
        for (int k = 0; k < 16; ++k) sm.row.u[row16][sub * 16 + k] = f2bf(uac[k] * inv);
    }
    __syncthreads();

    // 2. GRU gates: wave w owns output cols c0..c0+63; computes gi/gh for all
    //    three col-thirds so the GRU is lane-local (C-layout tiles j, j+16, j+32).
    f32x4 gi[3][4] = {}, gh[3][4] = {};
    for (int k0 = 0; k0 < 256; k0 += 32) {
        bf16x8 au = *(const bf16x8*)&sm.row.u[lr][k0 + lq * 8];
        bf16x8 ah = *(const bf16x8*)&sm.row.h[lr][k0 + lq * 8];
        #pragma unroll
        for (int tau = 0; tau < 3; ++tau)
            #pragma unroll
            for (int j = 0; j < 4; ++j) {
                const size_t boff = (size_t)(tau * 256 + c0 + j * 16 + lr) * 256 + k0 + lq * 8;
                gi[tau][j] = MFMA16(au, *(const bf16x8*)(p.wih_bf + boff), gi[tau][j]);
                gh[tau][j] = MFMA16(ah, *(const bf16x8*)(p.whh_bf + boff), gh[tau][j]);
            }
    }

    // 3. GRU elementwise (lane-local), overwrite s with slots_mid
    #pragma unroll
    for (int j = 0; j < 4; ++j) {
        const int c = c0 + j * 16 + lr;
        const float bir = p.bih[c], biz = p.bih[256 + c], bin_ = p.bih[512 + c];
        const float bhr = p.bhh[c], bhz = p.bhh[256 + c], bhn  = p.bhh[512 + c];
        #pragma unroll
        for (int r = 0; r < 4; ++r) {
            const int rw = lq * 4 + r;
            const float rg = 1.f / (1.f + __expf(-(gi[0][j][r] + bir + gh[0][j][r] + bhr)));
            const float z  = 1.f / (1.f + __expf(-(gi[1][j][r] + biz + gh[1][j][r] + bhz)));
            const float nn = tanhf(gi[2][j][r] + bin_ + rg * (gh[2][j][r] + bhn));
            const float h  = sm.row.s[rw][c];
            sm.row.s[rw][c] = (1.f - z) * nn + z * h;
        }
    }
    __syncthreads();

    // 4. LN_ff -> ff LDS bf16
    {
        float vals[16]; float s_ = 0.f, ss = 0.f;
        #pragma unroll
        for (int k = 0; k < 16; ++k) {
            const float v = sm.row.s[row16][sub * 16 + k];
            vals[k] = v; s_ += v; ss += v * v;
        }
        #pragma unroll
        for (int m = 1; m < 16; m <<= 1) { s_ += __shfl_xor(s_, m); ss += __shfl_xor(ss, m); }
        const float mean = s_ * (1.f / 256.f);
        const float var  = ss * (1.f / 256.f) - mean * mean;
        const float rstd = rsqrtf(var + 1e-5f);
        #pragma unroll
        for (int k = 0; k < 16; ++k) {
            const int c = sub * 16 + k;
            sm.row.ff[row16][c] = f2bf((vals[k] - mean) * rstd * p.ln_ff_g[c] + p.ln_ff_b[c]);
        }
    }
    __syncthreads();

    // 5. MLP: h1 = relu(ff @ w1^T + b1) in 2 halves; out-acc += h1 @ w2^T slice
    f32x4 oacc[4] = {};
    #pragma unroll 1
    for (int half = 0; half < 2; ++half) {
        f32x4 hacc[8] = {};
        for (int k0 = 0; k0 < 256; k0 += 32) {
            bf16x8 af = *(const bf16x8*)&sm.row.ff[lr][k0 + lq * 8];
            #pragma unroll
            for (int j = 0; j < 8; ++j) {
                bf16x8 bv = *(const bf16x8*)(p.w1_bf + (size_t)(half * 512 + w * 128 + j * 16 + lr) * 256 + k0 + lq * 8);
                hacc[j] = MFMA16(af, bv, hacc[j]);
            }
        }
        #pragma unroll
        for (int j = 0; j < 8; ++j) {
            const int cl = w * 128 + j * 16 + lr;
            const float bb = p.b1[half * 512 + cl];
            #pragma unroll
            for (int r = 0; r < 4; ++r)
                sm.row.h1[lq * 4 + r][cl] = f2bf(fmaxf(hacc[j][r] + bb, 0.f));
        }
        __syncthreads();
        for (int k0 = 0; k0 < 512; k0 += 32) {
            bf16x8 a1 = *(const bf16x8*)&sm.row.h1[lr][k0 + lq * 8];
            #pragma unroll
            for (int j = 0; j < 4; ++j) {
                bf16x8 bv = *(const bf16x8*)(p.w2_bf + (size_t)(c0 + j * 16 + lr) * 1024 + half * 512 + k0 + lq * 8);
                oacc[j] = MFMA16(a1, bv, oacc[j]);
            }
        }
        __syncthreads();
    }

    // 6. out = mlp + b2 + slots_mid; write slots (and d_out on last iter)
    const bool last = (it == 2);
    #pragma unroll
    for (int j = 0; j < 4; ++j) {
        const int c = c0 + j * 16 + lr;
        const float bb = p.b2[c];
        #pragma unroll
        for (int r = 0; r < 4; ++r) {
            const int rw = lq * 4 + r;
            const float val = oacc[j][r] + bb + sm.row.s[rw][c];
            sm.row.s[rw][c] = val;
            p.slots[(size_t)(r0 + rw) * 256 + c] = val;
            if (last) p.out[(size_t)(r0 + rw) * 256 + c] = val;
        }
    }
    if (last) return;
    __syncthreads();

    // 7. LN(slots_new) -> u LDS; q for next iteration
    {
        float vals[16]; float s_ = 0.f, ss = 0.f;
        #pragma unroll
        for (int k = 0; k < 16; ++k) {
            const float v = sm.row.s[row16][sub * 16 + k];
            vals[k] = v; s_ += v; ss += v * v;
        }
        #pragma unroll
        for (int m = 1; m < 16; m <<= 1) { s_ += __shfl_xor(s_, m); ss += __shfl_xor(ss, m); }
        const float mean = s_ * (1.f / 256.f);
        const float var  = ss * (1.f / 256.f) - mean * mean;
        const float rstd = rsqrtf(var + 1e-5f);
        #pragma unroll
        for (int k = 0; k < 16; ++k) {
            const int c = sub * 16 + k;
            sm.row.u[row16][c] = f2bf((vals[k] - mean) * rstd * p.ln_s_g[c] + p.ln_s_b[c]);
        }
    }
    __syncthreads();
    qgemm(p, sm, r0);
}

// ---------------------------------------------------------------------------
__global__ __launch_bounds__(256, 2) void fused(Params p) {
    __shared__ Smem sm;
    const int bid = blockIdx.x, t = threadIdx.x;
    unsigned ph = 0;

    // ---- P0: weights -> bf16, slots init, LN(inputs) -> bf16
    for (int gid = bid * 256 + t; gid < 1179648; gid += 131072) {
        if      (gid <   65536) p.kvW_bf[gid]          = f2bf(p.Wk[gid]);
        else if (gid <  131072) p.kvW_bf[gid]          = f2bf(p.Wv[gid -   65536]);
        else if (gid <  196608) p.Wq_bf[gid - 131072]  = f2bf(p.Wq[gid -  131072]);
        else if (gid <  393216) p.wih_bf[gid - 196608] = f2bf(p.wih[gid - 196608]);
        else if (gid <  589824) p.whh_bf[gid - 393216] = f2bf(p.whh[gid - 393216]);
        else if (gid <  851968) p.w1_bf[gid - 589824]  = f2bf(p.w1[gid -  589824]);
        else if (gid < 1114112) p.w2_bf[gid - 851968]  = f2bf(p.w2[gid -  851968]);
        else {
            const int i = gid - 1114112;
            const int d = i & 255;
            p.slots[i] = p.mu[d] + expf(p.ls[d]) * p.noise[i];
        }
    }
    ln_input(p);
    gridbar(p.bar, ++ph);

    // ---- P1: kv GEMM (1024 tiles, 2/block) + initial q (blocks 0..15)
    for (int tt = bid; tt < 1024; tt += 512) kv_tile(p, sm, tt);
    if (bid < 16) { __syncthreads(); init_q(p, sm, bid); }
    gridbar(p.bar, ++ph);

    // ---- 3 slot-attention iterations
    for (int it = 0; it < 3; ++it) {
        attn_phase(p, sm, bid);
        gridbar(p.bar, ++ph);
        if (bid < 16) row_phase(p, sm, bid, it);
        if (it < 2) gridbar(p.bar, ++ph);
    }
}

// ---------------------------------------------------------------------------
extern "C" void kernel_launch(void* const* d_in, const int* in_sizes, int n_in,
                              void* d_out, int out_size, void* d_ws, size_t ws_size,
                              hipStream_t stream)
{
    (void)in_sizes; (void)n_in; (void)out_size; (void)ws_size;

    Params prm;
    prm.inputs  = (const float*)d_in[0];
    prm.noise   = (const float*)d_in[1];
    prm.mu      = (const float*)d_in[2];
    prm.ls      = (const float*)d_in[3];
    prm.Wq      = (const float*)d_in[4];
    prm.Wk      = (const float*)d_in[5];
    prm.Wv      = (const float*)d_in[6];
    prm.wih     = (const float*)d_in[7];
    prm.whh     = (const float*)d_in[8];
    prm.bih     = (const float*)d_in[9];
    prm.bhh     = (const float*)d_in[10];
    prm.w1      = (const float*)d_in[11];
    prm.b1      = (const float*)d_in[12];
    prm.w2      = (const float*)d_in[13];
    prm.b2      = (const float*)d_in[14];
    prm.ln_in_g = (const float*)d_in[15];
    prm.ln_in_b = (const float*)d_in[16];
    prm.ln_s_g  = (const float*)d_in[17];
    prm.ln_s_b  = (const float*)d_in[18];
    prm.ln_ff_g = (const float*)d_in[19];
    prm.ln_ff_b = (const float*)d_in[20];
    prm.out     = (float*)d_out;

    char* ptr = (char*)d_ws;
    auto alloc = [&](size_t bytes) -> char* {
        char* r = ptr; ptr += (bytes + 255) & ~(size_t)255; return r;
    };
    prm.bar    = (unsigned*)      alloc(8192);
    prm.x_bf   = (unsigned short*)alloc((size_t)32768 * 256 * 2);
    prm.kv     = (float*)         alloc((size_t)32768 * 512 * 4);
    prm.kvW_bf = (unsigned short*)alloc(512 * 256 * 2);
    prm.Wq_bf  = (unsigned short*)alloc(256 * 256 * 2);
    prm.wih_bf = (unsigned short*)alloc(768 * 256 * 2);
    prm.whh_bf = (unsigned short*)alloc(768 * 256 * 2);
    prm.w1_bf  = (unsigned short*)alloc(1024 * 256 * 2);
    prm.w2_bf  = (unsigned short*)alloc(256 * 1024 * 2);
    prm.slots  = (float*)         alloc(256 * 256 * 4);
    prm.q      = (float*)         alloc(256 * 256 * 4);
    prm.upart  = (float*)         alloc((size_t)32 * 16 * 8 * 256 * 4);
    prm.rspart = (float*)         alloc(32 * 16 * 8 * 4);

    hipMemsetAsync(prm.bar, 0, 8192, stream);
    fused<<<dim3(512), dim3(256), 0, stream>>>(prm);
}

// Round 6
// 464.159 us; speedup vs baseline: 1.5641x; 1.5641x over previous
//
#include <hip/hip_runtime.h>

// ---------------------------------------------------------------------------
// SlotAttention on MI355X (gfx950) — back to HARDWARE kernel-boundary sync.
// Rounds 2-5 proved: software grid barriers on 8 non-coherent L2s plateau at
// ~60-70us each regardless of design (664/600/627us); round 0's 30 HW launches
// did the same work in 350us. Keep the round-2..5 phase *fusion* and proven
// math, sync with kernel boundaries: 8 launches total.
//   K1 prep:   weights->bf16 + slots init + LN(inputs)->bf16     (4608 blocks)
//   K2 kv:     kv = x_ln @ [Wk;Wv]^T (1024 tiles) + init q (16)  (1040 blocks)
//   3x K3 attn: dots+softmax+partials, 32 b x 16 chunks of 64    (512 blocks)
//      K4 row:  combine+GRU+LN+MLP+residual+LN+next-q            (16 blocks)
// De-fusing also shrinks per-kernel VGPR/LDS (attn ~12KB LDS vs 58KB union).
// MFMA fragment layouts per learn_hip m89/m97 (ref-verified):
//   A/B operand: idx = lane&15 (m or n), k = (lane>>4)*8 + j
//   C/D:         col = lane&15, row = (lane>>4)*4 + reg
// kv-GEMM LDS tiles XOR-swizzled (slot ^= (row>>1)&3): read conflicts 8->2 way.
// ---------------------------------------------------------------------------

typedef __attribute__((ext_vector_type(8))) __bf16 bf16x8;
typedef __attribute__((ext_vector_type(4))) float  f32x4;

#define MFMA16(a, b, c) __builtin_amdgcn_mfma_f32_16x16x32_bf16((a), (b), (c), 0, 0, 0)

static __device__ __forceinline__ unsigned short f2bf(float f) {
    unsigned int x = __float_as_uint(f);
    x = (x + 0x7fffu + ((x >> 16) & 1u)) >> 16;   // RN-even
    return (unsigned short)x;
}

struct Params {
    const float *inputs, *noise, *mu, *ls;
    const float *Wq, *Wk, *Wv, *wih, *whh, *bih, *bhh, *w1, *b1, *w2, *b2;
    const float *ln_in_g, *ln_in_b, *ln_s_g, *ln_s_b, *ln_ff_g, *ln_ff_b;
    float* out;
    unsigned short *x_bf, *kvW_bf, *Wq_bf, *wih_bf, *whh_bf, *w1_bf, *w2_bf;
    float *kv, *slots, *q, *upart, *rspart;
};

// ---------------- q = ln_s(16 rows in u) @ Wq^T -----------------------------
static __device__ void qgemm(const Params& p, const unsigned short (&u)[16][264], int r0) {
    const int t = threadIdx.x, w = t >> 6, lane = t & 63;
    const int lr = lane & 15, lq = lane >> 4;
    f32x4 acc[4] = {};
    for (int k0 = 0; k0 < 256; k0 += 32) {
        bf16x8 a = *(const bf16x8*)&u[lr][k0 + lq * 8];
        #pragma unroll
        for (int j = 0; j < 4; ++j) {
            bf16x8 bv = *(const bf16x8*)(p.Wq_bf + (size_t)(w * 64 + j * 16 + lr) * 256 + k0 + lq * 8);
            acc[j] = MFMA16(a, bv, acc[j]);
        }
    }
    #pragma unroll
    for (int j = 0; j < 4; ++j)
        #pragma unroll
        for (int r = 0; r < 4; ++r)
            p.q[(size_t)(r0 + lq * 4 + r) * 256 + w * 64 + j * 16 + lr] = acc[j][r];
}

// ============================ K1: prep + LN(inputs) =========================
__global__ __launch_bounds__(256) void k_prep(Params p) {
    const int bid = blockIdx.x, t = threadIdx.x;
    // weights -> bf16, slots init (exactly one element per thread at 4608 blocks)
    for (int gid = bid * 256 + t; gid < 1179648; gid += 4608 * 256) {
        if      (gid <   65536) p.kvW_bf[gid]          = f2bf(p.Wk[gid]);
        else if (gid <  131072) p.kvW_bf[gid]          = f2bf(p.Wv[gid -   65536]);
        else if (gid <  196608) p.Wq_bf[gid - 131072]  = f2bf(p.Wq[gid -  131072]);
        else if (gid <  393216) p.wih_bf[gid - 196608] = f2bf(p.wih[gid - 196608]);
        else if (gid <  589824) p.whh_bf[gid - 393216] = f2bf(p.whh[gid - 393216]);
        else if (gid <  851968) p.w1_bf[gid - 589824]  = f2bf(p.w1[gid -  589824]);
        else if (gid < 1114112) p.w2_bf[gid - 851968]  = f2bf(p.w2[gid -  851968]);
        else {
            const int i = gid - 1114112;
            const int d = i & 255;
            p.slots[i] = p.mu[d] + expf(p.ls[d]) * p.noise[i];
        }
    }
    // LN(inputs) rows -> bf16, one row per wave, stride 18432 waves
    const int wid  = (bid * 256 + t) >> 6;
    const int lane = t & 63;
    const float g0 = p.ln_in_g[lane * 4 + 0], g1 = p.ln_in_g[lane * 4 + 1];
    const float g2 = p.ln_in_g[lane * 4 + 2], g3 = p.ln_in_g[lane * 4 + 3];
    const float b0 = p.ln_in_b[lane * 4 + 0], b1 = p.ln_in_b[lane * 4 + 1];
    const float b2 = p.ln_in_b[lane * 4 + 2], b3 = p.ln_in_b[lane * 4 + 3];
    #pragma unroll 2
    for (int row = wid; row < 32768; row += 18432) {
        float4 v = *(const float4*)(p.inputs + (size_t)row * 256 + lane * 4);
        float s  = v.x + v.y + v.z + v.w;
        float ss = v.x * v.x + v.y * v.y + v.z * v.z + v.w * v.w;
        #pragma unroll
        for (int o = 1; o < 64; o <<= 1) { s += __shfl_xor(s, o); ss += __shfl_xor(ss, o); }
        float mean = s * (1.f / 256.f);
        float var  = ss * (1.f / 256.f) - mean * mean;
        float rstd = rsqrtf(var + 1e-5f);
        ushort4 o4;
        o4.x = f2bf((v.x - mean) * rstd * g0 + b0);
        o4.y = f2bf((v.y - mean) * rstd * g1 + b1);
        o4.z = f2bf((v.z - mean) * rstd * g2 + b2);
        o4.w = f2bf((v.w - mean) * rstd * g3 + b3);
        *(ushort4*)(p.x_bf + (size_t)row * 256 + lane * 4) = o4;
    }
}

// ============================ K2: kv GEMM + init q ==========================
union KvSmem {
    struct { unsigned short As[128 * 32], Bs[128 * 32]; } g;   // 16 KB
    unsigned short u[16][264];                                  // 8.25 KB
};

__global__ __launch_bounds__(256) void k_kv(Params p) {
    __shared__ KvSmem sm;
    const int bid = blockIdx.x, t = threadIdx.x;
    if (bid < 1024) {
        // ---- one 128x128 kv tile
        const int m0 = (bid >> 2) * 128, n0 = (bid & 3) * 128;
        const int wave = t >> 6, lane = t & 63;
        const int qr = (wave >> 1) * 64, qc = (wave & 1) * 64;
        const int lr = lane & 15, lq = lane >> 4;
        f32x4 acc[4][4] = {};
        const int sr = t >> 2, sl = t & 3, gk = sl * 8;
        const int wsl0 = (sl ^ ((sr >> 1) & 3)) * 8;           // swizzled slots
        const int wsl1 = (sl ^ (((sr + 64) >> 1) & 3)) * 8;
        for (int k0 = 0; k0 < 256; k0 += 32) {
            __syncthreads();
            uint4 a0 = *(const uint4*)(p.x_bf   + (size_t)(m0 + sr)      * 256 + k0 + gk);
            uint4 a1 = *(const uint4*)(p.x_bf   + (size_t)(m0 + sr + 64) * 256 + k0 + gk);
            uint4 b0 = *(const uint4*)(p.kvW_bf + (size_t)(n0 + sr)      * 256 + k0 + gk);
            uint4 b1 = *(const uint4*)(p.kvW_bf + (size_t)(n0 + sr + 64) * 256 + k0 + gk);
            *(uint4*)(sm.g.As + sr * 32 + wsl0) = a0;
            *(uint4*)(sm.g.As + (sr + 64) * 32 + wsl1) = a1;
            *(uint4*)(sm.g.Bs + sr * 32 + wsl0) = b0;
            *(uint4*)(sm.g.Bs + (sr + 64) * 32 + wsl1) = b1;
            __syncthreads();
            bf16x8 af[4], bv[4];
            #pragma unroll
            for (int i = 0; i < 4; i++) {
                const int ra = qr + i * 16 + lr;
                af[i] = *(const bf16x8*)(sm.g.As + ra * 32 + ((lq ^ ((ra >> 1) & 3)) * 8));
            }
            #pragma unroll
            for (int i = 0; i < 4; i++) {
                const int rb = qc + i * 16 + lr;
                bv[i] = *(const bf16x8*)(sm.g.Bs + rb * 32 + ((lq ^ ((rb >> 1) & 3)) * 8));
            }
            #pragma unroll
            for (int i = 0; i < 4; i++)
                #pragma unroll
                for (int j = 0; j < 4; j++)
                    acc[i][j] = MFMA16(af[i], bv[j], acc[i][j]);
        }
        #pragma unroll
        for (int i = 0; i < 4; i++)
            #pragma unroll
            for (int j = 0; j < 4; j++) {
                const int col = n0 + qc + j * 16 + lr;
                #pragma unroll
                for (int r = 0; r < 4; r++) {
                    const int rw = m0 + qr + i * 16 + lq * 4 + r;
                    p.kv[(size_t)rw * 512 + col] = acc[i][j][r];
                }
            }
    } else {
        // ---- init q: LN(slots) -> u LDS -> qgemm, blocks 1024..1039
        const int r0 = (bid - 1024) * 16;
        const int row16 = t >> 4, sub = t & 15;
        float vals[16]; float s = 0.f, ss = 0.f;
        #pragma unroll
        for (int k = 0; k < 16; k += 4) {
            float4 v = *(const float4*)(p.slots + (size_t)(r0 + row16) * 256 + sub * 16 + k);
            vals[k] = v.x; vals[k + 1] = v.y; vals[k + 2] = v.z; vals[k + 3] = v.w;
            s += v.x + v.y + v.z + v.w;
            ss += v.x * v.x + v.y * v.y + v.z * v.z + v.w * v.w;
        }
        #pragma unroll
        for (int m = 1; m < 16; m <<= 1) { s += __shfl_xor(s, m); ss += __shfl_xor(ss, m); }
        const float mean = s * (1.f / 256.f);
        const float var  = ss * (1.f / 256.f) - mean * mean;
        const float rstd = rsqrtf(var + 1e-5f);
        #pragma unroll
        for (int k = 0; k < 16; ++k) {
            const int c = sub * 16 + k;
            sm.u[row16][c] = f2bf((vals[k] - mean) * rstd * p.ln_s_g[c] + p.ln_s_b[c]);
        }
        __syncthreads();
        qgemm(p, sm.u, r0);
    }
}

// ============================ K3: attention =================================
// 512 blocks: b = bid>>4 (32 batches), chunk = bid&15 (16 chunks of 64 tokens).
__global__ __launch_bounds__(256) void k_attn(Params p) {
    __shared__ float q_s[8][260];
    __shared__ float sc[8][68];
    const int bid = blockIdx.x, t = threadIdx.x;
    const int b = bid >> 4, chunk = bid & 15, j0 = chunk * 64;
    {   // q rows for this batch (8 x 256 f32)
        const int i = t >> 5, c0 = (t & 31) * 8;
        const float* qr = p.q + (size_t)(b * 8 + i) * 256 + c0;
        *(float4*)&q_s[i][c0]     = *(const float4*)(qr);
        *(float4*)&q_s[i][c0 + 4] = *(const float4*)(qr + 4);
    }
    __syncthreads();
    {   // dots for 64 tokens x 8 slots
        const int i = t & 7, jj = t >> 3;          // jj: 0..31
        const float4* qrow = (const float4*)&q_s[i][0];
        #pragma unroll 1
        for (int g = 0; g < 2; ++g) {
            const int jl = g * 32 + jj;
            const float4* krow = (const float4*)(p.kv + ((size_t)b * 1024 + j0 + jl) * 512);
            float a0 = 0, a1 = 0, a2 = 0, a3 = 0;
            #pragma unroll 8
            for (int dd = 0; dd < 64; ++dd) {
                float4 qv = qrow[dd], kk = krow[dd];
                a0 += qv.x * kk.x; a1 += qv.y * kk.y; a2 += qv.z * kk.z; a3 += qv.w * kk.w;
            }
            sc[i][jl] = (a0 + a1 + a2 + a3) * 0.0625f;   // SCALE = 256^-0.5
        }
    }
    __syncthreads();
    if (t < 64) {   // softmax over slots per token + EPS
        float v[8], m = -1e30f;
        #pragma unroll
        for (int ii = 0; ii < 8; ++ii) { v[ii] = sc[ii][t]; m = fmaxf(m, v[ii]); }
        float s = 0.f;
        #pragma unroll
        for (int ii = 0; ii < 8; ++ii) { v[ii] = __expf(v[ii] - m); s += v[ii]; }
        const float inv = 1.f / s;
        #pragma unroll
        for (int ii = 0; ii < 8; ++ii) sc[ii][t] = v[ii] * inv + 1e-8f;
    }
    __syncthreads();
    if (t < 8) {    // per-slot row-sum partial over this 64-token chunk
        float s = 0.f;
        for (int jl = 0; jl < 64; ++jl) s += sc[t][jl];
        p.rspart[((size_t)b * 16 + chunk) * 8 + t] = s;
    }
    {   // partial updates: acc[i] += w[i][j] * v[j][d], d = t
        float acc[8] = {};
        const float* vbase = p.kv + ((size_t)b * 1024 + j0) * 512 + 256 + t;
        #pragma unroll 8
        for (int jl = 0; jl < 64; ++jl) {
            const float vv = vbase[(size_t)jl * 512];
            #pragma unroll
            for (int ii = 0; ii < 8; ++ii) acc[ii] += sc[ii][jl] * vv;
        }
        float* up = p.upart + (((size_t)b * 16 + chunk) * 8) * 256 + t;
        #pragma unroll
        for (int ii = 0; ii < 8; ++ii) up[(size_t)ii * 256] = acc[ii];
    }
}

// ============================ K4: row chain =================================
struct RowSmem {
    unsigned short u[16][264];     // combine result / ln_s (bf16, pad +8)
    unsigned short h[16][264];     // slots_prev bf16
    unsigned short ff[16][264];    // LN_ff out bf16
    unsigned short h1[16][520];    // half of MLP hidden (512 + 8 pad)
    float          s[16][260];     // slots f32 (prev -> mid -> new)
};

template<int LAST>
__global__ __launch_bounds__(256) void k_row(Params p) {
    __shared__ RowSmem sm;
    const int bid = blockIdx.x, t = threadIdx.x;
    const int r0 = bid * 16;
    const int lane = t & 63, w = t >> 6;
    const int lr = lane & 15, lq = lane >> 4;
    const int row16 = t >> 4, sub = t & 15;
    const int c0 = w * 64;

    // 1. slots f32 -> s LDS (+ bf16 h LDS); combine upart/rspart -> u LDS bf16
    #pragma unroll
    for (int k = 0; k < 16; k += 4) {
        float4 v = *(const float4*)(p.slots + (size_t)(r0 + row16) * 256 + sub * 16 + k);
        *(float4*)&sm.s[row16][sub * 16 + k] = v;
        sm.h[row16][sub * 16 + k]     = f2bf(v.x);
        sm.h[row16][sub * 16 + k + 1] = f2bf(v.y);
        sm.h[row16][sub * 16 + k + 2] = f2bf(v.z);
        sm.h[row16][sub * 16 + k + 3] = f2bf(v.w);
    }
    {
        const int grow = r0 + row16, bb = grow >> 3, ii = grow & 7;
        float rs = 0.f;
        #pragma unroll
        for (int c = 0; c < 16; ++c) rs += p.rspart[((size_t)bb * 16 + c) * 8 + ii];
        const float inv = 1.f / rs;
        float uac[16] = {};
        #pragma unroll
        for (int c = 0; c < 16; ++c) {
            const float* up = p.upart + (((size_t)bb * 16 + c) * 8 + ii) * 256 + sub * 16;
            #pragma unroll
            for (int k = 0; k < 16; k += 4) {
                float4 v = *(const float4*)(up + k);
                uac[k] += v.x; uac[k + 1] += v.y; uac[k + 2] += v.z; uac[k + 3] += v.w;
            }
        }
        #pragma unroll
        for (int k = 0; k < 16; ++k) sm.u[row16][sub * 16 + k] = f2bf(uac[k] * inv);
    }
    __syncthreads();

    // 2. GRU gates: wave w owns output cols c0..c0+63 (C-layout tiles j,j+16,j+32)
    f32x4 gi[3][4] = {}, gh[3][4] = {};
    for (int k0 = 0; k0 < 256; k0 += 32) {
        bf16x8 au = *(const bf16x8*)&sm.u[lr][k0 + lq * 8];
        bf16x8 ah = *(const bf16x8*)&sm.h[lr][k0 + lq * 8];
        #pragma unroll
        for (int tau = 0; tau < 3; ++tau)
            #pragma unroll
            for (int j = 0; j < 4; ++j) {
                const size_t boff = (size_t)(tau * 256 + c0 + j * 16 + lr) * 256 + k0 + lq * 8;
                gi[tau][j] = MFMA16(au, *(const bf16x8*)(p.wih_bf + boff), gi[tau][j]);
                gh[tau][j] = MFMA16(ah, *(const bf16x8*)(p.whh_bf + boff), gh[tau][j]);
            }
    }

    // 3. GRU elementwise (lane-local), overwrite s with slots_mid
    #pragma unroll
    for (int j = 0; j < 4; ++j) {
        const int c = c0 + j * 16 + lr;
        const float bir = p.bih[c], biz = p.bih[256 + c], bin_ = p.bih[512 + c];
        const float bhr = p.bhh[c], bhz = p.bhh[256 + c], bhn  = p.bhh[512 + c];
        #pragma unroll
        for (int r = 0; r < 4; ++r) {
            const int rw = lq * 4 + r;
            const float rg = 1.f / (1.f + __expf(-(gi[0][j][r] + bir + gh[0][j][r] + bhr)));
            const float z  = 1.f / (1.f + __expf(-(gi[1][j][r] + biz + gh[1][j][r] + bhz)));
            const float nn = tanhf(gi[2][j][r] + bin_ + rg * (gh[2][j][r] + bhn));
            const float h  = sm.s[rw][c];
            sm.s[rw][c] = (1.f - z) * nn + z * h;
        }
    }
    __syncthreads();

    // 4. LN_ff -> ff LDS bf16
    {
        float vals[16]; float s_ = 0.f, ss = 0.f;
        #pragma unroll
        for (int k = 0; k < 16; ++k) {
            const float v = sm.s[row16][sub * 16 + k];
            vals[k] = v; s_ += v; ss += v * v;
        }
        #pragma unroll
        for (int m = 1; m < 16; m <<= 1) { s_ += __shfl_xor(s_, m); ss += __shfl_xor(ss, m); }
        const float mean = s_ * (1.f / 256.f);
        const float var  = ss * (1.f / 256.f) - mean * mean;
        const float rstd = rsqrtf(var + 1e-5f);
        #pragma unroll
        for (int k = 0; k < 16; ++k) {
            const int c = sub * 16 + k;
            sm.ff[row16][c] = f2bf((vals[k] - mean) * rstd * p.ln_ff_g[c] + p.ln_ff_b[c]);
        }
    }
    __syncthreads();

    // 5. MLP: h1 = relu(ff @ w1^T + b1) in 2 halves; out-acc += h1 @ w2^T slice
    f32x4 oacc[4] = {};
    #pragma unroll 1
    for (int half = 0; half < 2; ++half) {
        f32x4 hacc[8] = {};
        for (int k0 = 0; k0 < 256; k0 += 32) {
            bf16x8 af = *(const bf16x8*)&sm.ff[lr][k0 + lq * 8];
            #pragma unroll
            for (int j = 0; j < 8; ++j) {
                bf16x8 bv = *(const bf16x8*)(p.w1_bf + (size_t)(half * 512 + w * 128 + j * 16 + lr) * 256 + k0 + lq * 8);
                hacc[j] = MFMA16(af, bv, hacc[j]);
            }
        }
        #pragma unroll
        for (int j = 0; j < 8; ++j) {
            const int cl = w * 128 + j * 16 + lr;
            const float bb = p.b1[half * 512 + cl];
            #pragma unroll
            for (int r = 0; r < 4; ++r)
                sm.h1[lq * 4 + r][cl] = f2bf(fmaxf(hacc[j][r] + bb, 0.f));
        }
        __syncthreads();
        for (int k0 = 0; k0 < 512; k0 += 32) {
            bf16x8 a1 = *(const bf16x8*)&sm.h1[lr][k0 + lq * 8];
            #pragma unroll
            for (int j = 0; j < 4; ++j) {
                bf16x8 bv = *(const bf16x8*)(p.w2_bf + (size_t)(c0 + j * 16 + lr) * 1024 + half * 512 + k0 + lq * 8);
                oacc[j] = MFMA16(a1, bv, oacc[j]);
            }
        }
        __syncthreads();
    }

    // 6. out = mlp + b2 + slots_mid; write slots (and d_out on last iter)
    #pragma unroll
    for (int j = 0; j < 4; ++j) {
        const int c = c0 + j * 16 + lr;
        const float bb = p.b2[c];
        #pragma unroll
        for (int r = 0; r < 4; ++r) {
            const int rw = lq * 4 + r;
            const float val = oacc[j][r] + bb + sm.s[rw][c];
            sm.s[rw][c] = val;
            p.slots[(size_t)(r0 + rw) * 256 + c] = val;
            if (LAST) p.out[(size_t)(r0 + rw) * 256 + c] = val;
        }
    }
    if (LAST) return;
    __syncthreads();

    // 7. LN(slots_new) -> u LDS; q for next iteration
    {
        float vals[16]; float s_ = 0.f, ss = 0.f;
        #pragma unroll
        for (int k = 0; k < 16; ++k) {
            const float v = sm.s[row16][sub * 16 + k];
            vals[k] = v; s_ += v; ss += v * v;
        }
        #pragma unroll
        for (int m = 1; m < 16; m <<= 1) { s_ += __shfl_xor(s_, m); ss += __shfl_xor(ss, m); }
        const float mean = s_ * (1.f / 256.f);
        const float var  = ss * (1.f / 256.f) - mean * mean;
        const float rstd = rsqrtf(var + 1e-5f);
        #pragma unroll
        for (int k = 0; k < 16; ++k) {
            const int c = sub * 16 + k;
            sm.u[row16][c] = f2bf((vals[k] - mean) * rstd * p.ln_s_g[c] + p.ln_s_b[c]);
        }
    }
    __syncthreads();
    qgemm(p, sm.u, r0);
}

// ---------------------------------------------------------------------------
extern "C" void kernel_launch(void* const* d_in, const int* in_sizes, int n_in,
                              void* d_out, int out_size, void* d_ws, size_t ws_size,
                              hipStream_t stream)
{
    (void)in_sizes; (void)n_in; (void)out_size; (void)ws_size;

    Params prm;
    prm.inputs  = (const float*)d_in[0];
    prm.noise   = (const float*)d_in[1];
    prm.mu      = (const float*)d_in[2];
    prm.ls      = (const float*)d_in[3];
    prm.Wq      = (const float*)d_in[4];
    prm.Wk      = (const float*)d_in[5];
    prm.Wv      = (const float*)d_in[6];
    prm.wih     = (const float*)d_in[7];
    prm.whh     = (const float*)d_in[8];
    prm.bih     = (const float*)d_in[9];
    prm.bhh     = (const float*)d_in[10];
    prm.w1      = (const float*)d_in[11];
    prm.b1      = (const float*)d_in[12];
    prm.w2      = (const float*)d_in[13];
    prm.b2      = (const float*)d_in[14];
    prm.ln_in_g = (const float*)d_in[15];
    prm.ln_in_b = (const float*)d_in[16];
    prm.ln_s_g  = (const float*)d_in[17];
    prm.ln_s_b  = (const float*)d_in[18];
    prm.ln_ff_g = (const float*)d_in[19];
    prm.ln_ff_b = (const float*)d_in[20];
    prm.out     = (float*)d_out;

    char* ptr = (char*)d_ws;
    auto alloc = [&](size_t bytes) -> char* {
        char* r = ptr; ptr += (bytes + 255) & ~(size_t)255; return r;
    };
    prm.x_bf   = (unsigned short*)alloc((size_t)32768 * 256 * 2);
    prm.kv     = (float*)         alloc((size_t)32768 * 512 * 4);
    prm.kvW_bf = (unsigned short*)alloc(512 * 256 * 2);
    prm.Wq_bf  = (unsigned short*)alloc(256 * 256 * 2);
    prm.wih_bf = (unsigned short*)alloc(768 * 256 * 2);
    prm.whh_bf = (unsigned short*)alloc(768 * 256 * 2);
    prm.w1_bf  = (unsigned short*)alloc(1024 * 256 * 2);
    prm.w2_bf  = (unsigned short*)alloc(256 * 1024 * 2);
    prm.slots  = (float*)         alloc(256 * 256 * 4);
    prm.q      = (float*)         alloc(256 * 256 * 4);
    prm.upart  = (float*)         alloc((size_t)32 * 16 * 8 * 256 * 4);
    prm.rspart = (float*)         alloc(32 * 16 * 8 * 4);

    k_prep<<<4608, 256, 0, stream>>>(prm);
    k_kv  <<<1040, 256, 0, stream>>>(prm);
    for (int it = 0; it < 3; ++it) {
        k_attn<<<512, 256, 0, stream>>>(prm);
        if (it < 2) k_row<0><<<16, 256, 0, stream>>>(prm);
        else        k_row<1><<<16, 256, 0, stream>>>(prm);
    }
}

// Round 7
// 293.064 us; speedup vs baseline: 2.4772x; 1.5838x over previous
//
#include <hip/hip_runtime.h>

// ---------------------------------------------------------------------------
// SlotAttention on MI355X (gfx950) — HW kernel-boundary sync (round-6 lesson:
// software grid barriers plateau ~60-70us each; HW launches ~2us).
// Round-6 lesson #2: the fused 16-block k_row (95us x3) was latency-bound —
// 16 blocks streaming 1.8MB weights with no LDS staging. Split it back into
// staged-GEMM kernels with real parallelism (round-0 proven bodies):
//   per iter: attn(512) -> u2b(256) -> gates(96) -> gruln(256) -> mlp1(64)
//             -> out(64: 16 strips x 4 K-chunks) -> lnq(16)
// kv stored bf16 (halves attn fetch + kv write; absmax headroom 3x).
// MFMA fragment layouts per learn_hip m89/m97 (ref-verified):
//   A/B operand: idx = lane&15 (m or n), k = (lane>>4)*8 + j
//   C/D:         col = lane&15, row = (lane>>4)*4 + reg
// GEMM LDS tiles XOR-swizzled (slot ^= (row>>1)&3): read conflicts 8->2 way.
// ---------------------------------------------------------------------------

typedef __attribute__((ext_vector_type(8))) __bf16 bf16x8;
typedef __attribute__((ext_vector_type(4))) float  f32x4;

#define MFMA16(a, b, c) __builtin_amdgcn_mfma_f32_16x16x32_bf16((a), (b), (c), 0, 0, 0)

static __device__ __forceinline__ unsigned short f2bf(float f) {
    unsigned int x = __float_as_uint(f);
    x = (x + 0x7fffu + ((x >> 16) & 1u)) >> 16;   // RN-even
    return (unsigned short)x;
}
static __device__ __forceinline__ float bf2f(unsigned short u) {
    return __uint_as_float((unsigned int)u << 16);
}
static __device__ __forceinline__ float bflo(unsigned int x) {
    return __uint_as_float(x << 16);
}
static __device__ __forceinline__ float bfhi(unsigned int x) {
    return __uint_as_float(x & 0xffff0000u);
}

struct Params {
    const float *inputs, *noise, *mu, *ls;
    const float *Wq, *Wk, *Wv, *wih, *whh, *bih, *bhh, *w1, *b1, *w2, *b2;
    const float *ln_in_g, *ln_in_b, *ln_s_g, *ln_s_b, *ln_ff_g, *ln_ff_b;
    float* out;
    unsigned short *x_bf, *kvW_bf, *Wq_bf, *wih_bf, *whh_bf, *w1_bf, *w2_bf;
    unsigned short *kv_bf, *u_bf, *h_bf, *ff_bf, *h1_bf;
    float *slots, *q, *upart, *rspart, *gi, *gh, *opart;
};

// ---------------- q = ln_s(16 rows in u) @ Wq^T -----------------------------
static __device__ void qgemm(const Params& p, const unsigned short (&u)[16][264], int r0) {
    const int t = threadIdx.x, w = t >> 6, lane = t & 63;
    const int lr = lane & 15, lq = lane >> 4;
    f32x4 acc[4] = {};
    for (int k0 = 0; k0 < 256; k0 += 32) {
        bf16x8 a = *(const bf16x8*)&u[lr][k0 + lq * 8];
        #pragma unroll
        for (int j = 0; j < 4; ++j) {
            bf16x8 bv = *(const bf16x8*)(p.Wq_bf + (size_t)(w * 64 + j * 16 + lr) * 256 + k0 + lq * 8);
            acc[j] = MFMA16(a, bv, acc[j]);
        }
    }
    #pragma unroll
    for (int j = 0; j < 4; ++j)
        #pragma unroll
        for (int r = 0; r < 4; ++r)
            p.q[(size_t)(r0 + lq * 4 + r) * 256 + w * 64 + j * 16 + lr] = acc[j][r];
}

// ============================ K1: prep + LN(inputs) =========================
__global__ __launch_bounds__(256) void k_prep(Params p) {
    const int bid = blockIdx.x, t = threadIdx.x;
    for (int gid = bid * 256 + t; gid < 1179648; gid += 4608 * 256) {
        if      (gid <   65536) p.kvW_bf[gid]          = f2bf(p.Wk[gid]);
        else if (gid <  131072) p.kvW_bf[gid]          = f2bf(p.Wv[gid -   65536]);
        else if (gid <  196608) p.Wq_bf[gid - 131072]  = f2bf(p.Wq[gid -  131072]);
        else if (gid <  393216) p.wih_bf[gid - 196608] = f2bf(p.wih[gid - 196608]);
        else if (gid <  589824) p.whh_bf[gid - 393216] = f2bf(p.whh[gid - 393216]);
        else if (gid <  851968) p.w1_bf[gid - 589824]  = f2bf(p.w1[gid -  589824]);
        else if (gid < 1114112) p.w2_bf[gid - 851968]  = f2bf(p.w2[gid -  851968]);
        else {
            const int i = gid - 1114112;
            const int d = i & 255;
            p.slots[i] = p.mu[d] + expf(p.ls[d]) * p.noise[i];
        }
    }
    // LN(inputs) rows -> bf16, one row per wave
    const int wid  = (bid * 256 + t) >> 6;
    const int lane = t & 63;
    const float g0 = p.ln_in_g[lane * 4 + 0], g1 = p.ln_in_g[lane * 4 + 1];
    const float g2 = p.ln_in_g[lane * 4 + 2], g3 = p.ln_in_g[lane * 4 + 3];
    const float b0 = p.ln_in_b[lane * 4 + 0], b1 = p.ln_in_b[lane * 4 + 1];
    const float b2 = p.ln_in_b[lane * 4 + 2], b3 = p.ln_in_b[lane * 4 + 3];
    #pragma unroll 2
    for (int row = wid; row < 32768; row += 18432) {
        float4 v = *(const float4*)(p.inputs + (size_t)row * 256 + lane * 4);
        float s  = v.x + v.y + v.z + v.w;
        float ss = v.x * v.x + v.y * v.y + v.z * v.z + v.w * v.w;
        #pragma unroll
        for (int o = 1; o < 64; o <<= 1) { s += __shfl_xor(s, o); ss += __shfl_xor(ss, o); }
        float mean = s * (1.f / 256.f);
        float var  = ss * (1.f / 256.f) - mean * mean;
        float rstd = rsqrtf(var + 1e-5f);
        ushort4 o4;
        o4.x = f2bf((v.x - mean) * rstd * g0 + b0);
        o4.y = f2bf((v.y - mean) * rstd * g1 + b1);
        o4.z = f2bf((v.z - mean) * rstd * g2 + b2);
        o4.w = f2bf((v.w - mean) * rstd * g3 + b3);
        *(ushort4*)(p.x_bf + (size_t)row * 256 + lane * 4) = o4;
    }
}

// ============================ K2: kv GEMM + init q ==========================
union KvSmem {
    struct { unsigned short As[128 * 32], Bs[128 * 32]; } g;   // 16 KB
    unsigned short u[16][264];                                  // 8.25 KB
};

__global__ __launch_bounds__(256) void k_kv(Params p) {
    __shared__ KvSmem sm;
    const int bid = blockIdx.x, t = threadIdx.x;
    if (bid < 1024) {
        const int m0 = (bid >> 2) * 128, n0 = (bid & 3) * 128;
        const int wave = t >> 6, lane = t & 63;
        const int qr = (wave >> 1) * 64, qc = (wave & 1) * 64;
        const int lr = lane & 15, lq = lane >> 4;
        f32x4 acc[4][4] = {};
        const int sr = t >> 2, sl = t & 3, gk = sl * 8;
        const int wsl0 = (sl ^ ((sr >> 1) & 3)) * 8;
        const int wsl1 = (sl ^ (((sr + 64) >> 1) & 3)) * 8;
        for (int k0 = 0; k0 < 256; k0 += 32) {
            __syncthreads();
            uint4 a0 = *(const uint4*)(p.x_bf   + (size_t)(m0 + sr)      * 256 + k0 + gk);
            uint4 a1 = *(const uint4*)(p.x_bf   + (size_t)(m0 + sr + 64) * 256 + k0 + gk);
            uint4 b0 = *(const uint4*)(p.kvW_bf + (size_t)(n0 + sr)      * 256 + k0 + gk);
            uint4 b1 = *(const uint4*)(p.kvW_bf + (size_t)(n0 + sr + 64) * 256 + k0 + gk);
            *(uint4*)(sm.g.As + sr * 32 + wsl0) = a0;
            *(uint4*)(sm.g.As + (sr + 64) * 32 + wsl1) = a1;
            *(uint4*)(sm.g.Bs + sr * 32 + wsl0) = b0;
            *(uint4*)(sm.g.Bs + (sr + 64) * 32 + wsl1) = b1;
            __syncthreads();
            bf16x8 af[4], bv[4];
            #pragma unroll
            for (int i = 0; i < 4; i++) {
                const int ra = qr + i * 16 + lr;
                af[i] = *(const bf16x8*)(sm.g.As + ra * 32 + ((lq ^ ((ra >> 1) & 3)) * 8));
            }
            #pragma unroll
            for (int i = 0; i < 4; i++) {
                const int rb = qc + i * 16 + lr;
                bv[i] = *(const bf16x8*)(sm.g.Bs + rb * 32 + ((lq ^ ((rb >> 1) & 3)) * 8));
            }
            #pragma unroll
            for (int i = 0; i < 4; i++)
                #pragma unroll
                for (int j = 0; j < 4; j++)
                    acc[i][j] = MFMA16(af[i], bv[j], acc[i][j]);
        }
        #pragma unroll
        for (int i = 0; i < 4; i++)
            #pragma unroll
            for (int j = 0; j < 4; j++) {
                const int col = n0 + qc + j * 16 + lr;
                #pragma unroll
                for (int r = 0; r < 4; r++) {
                    const int rw = m0 + qr + i * 16 + lq * 4 + r;
                    p.kv_bf[(size_t)rw * 512 + col] = f2bf(acc[i][j][r]);
                }
            }
    } else {
        // init q: LN(slots) -> u LDS -> qgemm, blocks 1024..1039
        const int r0 = (bid - 1024) * 16;
        const int row16 = t >> 4, sub = t & 15;
        float vals[16]; float s = 0.f, ss = 0.f;
        #pragma unroll
        for (int k = 0; k < 16; k += 4) {
            float4 v = *(const float4*)(p.slots + (size_t)(r0 + row16) * 256 + sub * 16 + k);
            vals[k] = v.x; vals[k + 1] = v.y; vals[k + 2] = v.z; vals[k + 3] = v.w;
            s += v.x + v.y + v.z + v.w;
            ss += v.x * v.x + v.y * v.y + v.z * v.z + v.w * v.w;
        }
        #pragma unroll
        for (int m = 1; m < 16; m <<= 1) { s += __shfl_xor(s, m); ss += __shfl_xor(ss, m); }
        const float mean = s * (1.f / 256.f);
        const float var  = ss * (1.f / 256.f) - mean * mean;
        const float rstd = rsqrtf(var + 1e-5f);
        #pragma unroll
        for (int k = 0; k < 16; ++k) {
            const int c = sub * 16 + k;
            sm.u[row16][c] = f2bf((vals[k] - mean) * rstd * p.ln_s_g[c] + p.ln_s_b[c]);
        }
        __syncthreads();
        qgemm(p, sm.u, r0);
    }
}

// ============================ K3: attention (bf16 kv) =======================
// 512 blocks: b = bid>>4 (32 batches), chunk = bid&15 (16 chunks of 64 tokens).
__global__ __launch_bounds__(256) void k_attn(Params p) {
    __shared__ float q_s[8][260];
    __shared__ float sc[8][68];
    const int bid = blockIdx.x, t = threadIdx.x;
    const int b = bid >> 4, chunk = bid & 15, j0 = chunk * 64;
    {   // q rows for this batch (8 x 256 f32)
        const int i = t >> 5, c0 = (t & 31) * 8;
        const float* qr = p.q + (size_t)(b * 8 + i) * 256 + c0;
        *(float4*)&q_s[i][c0]     = *(const float4*)(qr);
        *(float4*)&q_s[i][c0 + 4] = *(const float4*)(qr + 4);
    }
    __syncthreads();
    {   // dots for 64 tokens x 8 slots (k in bf16)
        const int i = t & 7, jj = t >> 3;
        const float4* qrow = (const float4*)&q_s[i][0];
        #pragma unroll 1
        for (int g = 0; g < 2; ++g) {
            const int jl = g * 32 + jj;
            const uint4* krow = (const uint4*)(p.kv_bf + ((size_t)b * 1024 + j0 + jl) * 512);
            float a0 = 0, a1 = 0, a2 = 0, a3 = 0;
            #pragma unroll 8
            for (int dd = 0; dd < 32; ++dd) {
                uint4 kk = krow[dd];
                float4 q0 = qrow[2 * dd], q1 = qrow[2 * dd + 1];
                a0 += q0.x * bflo(kk.x); a1 += q0.y * bfhi(kk.x);
                a2 += q0.z * bflo(kk.y); a3 += q0.w * bfhi(kk.y);
                a0 += q1.x * bflo(kk.z); a1 += q1.y * bfhi(kk.z);
                a2 += q1.z * bflo(kk.w); a3 += q1.w * bfhi(kk.w);
            }
            sc[i][jl] = (a0 + a1 + a2 + a3) * 0.0625f;   // SCALE = 256^-0.5
        }
    }
    __syncthreads();
    if (t < 64) {   // softmax over slots per token + EPS
        float v[8], m = -1e30f;
        #pragma unroll
        for (int ii = 0; ii < 8; ++ii) { v[ii] = sc[ii][t]; m = fmaxf(m, v[ii]); }
        float s = 0.f;
        #pragma unroll
        for (int ii = 0; ii < 8; ++ii) { v[ii] = __expf(v[ii] - m); s += v[ii]; }
        const float inv = 1.f / s;
        #pragma unroll
        for (int ii = 0; ii < 8; ++ii) sc[ii][t] = v[ii] * inv + 1e-8f;
    }
    __syncthreads();
    if (t < 8) {    // per-slot row-sum partial over this 64-token chunk
        float s = 0.f;
        for (int jl = 0; jl < 64; ++jl) s += sc[t][jl];
        p.rspart[((size_t)b * 16 + chunk) * 8 + t] = s;
    }
    {   // partial updates: acc[i] += w[i][j] * v[j][d], d = t (v in bf16)
        float acc[8] = {};
        const unsigned short* vbase = p.kv_bf + ((size_t)b * 1024 + j0) * 512 + 256 + t;
        #pragma unroll 8
        for (int jl = 0; jl < 64; ++jl) {
            const float vv = bf2f(vbase[(size_t)jl * 512]);
            #pragma unroll
            for (int ii = 0; ii < 8; ++ii) acc[ii] += sc[ii][jl] * vv;
        }
        float* up = p.upart + (((size_t)b * 16 + chunk) * 8) * 256 + t;
        #pragma unroll
        for (int ii = 0; ii < 8; ++ii) up[ii * 256] = acc[ii];
    }
}

// ============================ K4: combine -> u_bf, h_bf =====================
__global__ __launch_bounds__(256) void k_u2b(Params p) {
    const int row = blockIdx.x, t = threadIdx.x;
    const int b = row >> 3, i = row & 7;
    float acc = 0.f, rs = 0.f;
    #pragma unroll
    for (int c = 0; c < 16; ++c) {
        acc += p.upart[(((size_t)b * 16 + c) * 8 + i) * 256 + t];
        rs  += p.rspart[((size_t)b * 16 + c) * 8 + i];
    }
    const float inv = 1.f / rs;
    p.u_bf[(size_t)row * 256 + t] = f2bf(acc * inv);
    p.h_bf[(size_t)row * 256 + t] = f2bf(p.slots[(size_t)row * 256 + t]);
}

// ============================ K5: GRU gates GEMM ============================
// grid (4, 24): 64x64 tiles over C[256, 1536] = [gi | gh].
__global__ __launch_bounds__(256) void k_gates(Params p) {
    __shared__ unsigned short As[64 * 32], Bs[64 * 32];
    const int m0 = blockIdx.x * 64;
    const int n0g = blockIdx.y * 64;
    const bool isGi = n0g < 768;
    const int n0 = isGi ? n0g : n0g - 768;
    const unsigned short* A = isGi ? p.u_bf : p.h_bf;
    const unsigned short* B = isGi ? p.wih_bf : p.whh_bf;
    float* C = isGi ? p.gi : p.gh;
    const int t = threadIdx.x, wave = t >> 6, lane = t & 63;
    const int lr = lane & 15, lq = lane >> 4;
    f32x4 acc[4] = {};
    const int sr = t >> 2, sl = t & 3, gk = sl * 8;
    const int wsl = (sl ^ ((sr >> 1) & 3)) * 8;
    for (int k0 = 0; k0 < 256; k0 += 32) {
        __syncthreads();
        uint4 a0 = *(const uint4*)(A + (size_t)(m0 + sr) * 256 + k0 + gk);
        uint4 b0 = *(const uint4*)(B + (size_t)(n0 + sr) * 256 + k0 + gk);
        *(uint4*)(As + sr * 32 + wsl) = a0;
        *(uint4*)(Bs + sr * 32 + wsl) = b0;
        __syncthreads();
        const int ra = wave * 16 + lr;
        bf16x8 af = *(const bf16x8*)(As + ra * 32 + ((lq ^ ((ra >> 1) & 3)) * 8));
        #pragma unroll
        for (int j = 0; j < 4; ++j) {
            const int rb = j * 16 + lr;
            bf16x8 bv = *(const bf16x8*)(Bs + rb * 32 + ((lq ^ ((rb >> 1) & 3)) * 8));
            acc[j] = MFMA16(af, bv, acc[j]);
        }
    }
    #pragma unroll
    for (int j = 0; j < 4; ++j) {
        const int col = n0 + j * 16 + lr;
        #pragma unroll
        for (int r = 0; r < 4; ++r) {
            const int row = m0 + wave * 16 + lq * 4 + r;
            C[(size_t)row * 768 + col] = acc[j][r];
        }
    }
}

// ============================ K6: GRU elementwise + LN_ff ===================
__global__ __launch_bounds__(256) void k_gruln(Params p) {
    __shared__ float red[8];
    const int row = blockIdx.x, t = threadIdx.x;
    const float* gir = p.gi + (size_t)row * 768;
    const float* ghr = p.gh + (size_t)row * 768;
    const float ir  = gir[t]       + p.bih[t];
    const float iz  = gir[256 + t] + p.bih[256 + t];
    const float in_ = gir[512 + t] + p.bih[512 + t];
    const float hr  = ghr[t]       + p.bhh[t];
    const float hz  = ghr[256 + t] + p.bhh[256 + t];
    const float hn  = ghr[512 + t] + p.bhh[512 + t];
    const float r = 1.f / (1.f + __expf(-(ir + hr)));
    const float z = 1.f / (1.f + __expf(-(iz + hz)));
    const float n = tanhf(in_ + r * hn);
    const float h = p.slots[(size_t)row * 256 + t];
    const float s = (1.f - z) * n + z * h;
    p.slots[(size_t)row * 256 + t] = s;            // slots_mid (in place)
    float sm = s, ssq = s * s;
    #pragma unroll
    for (int o = 32; o > 0; o >>= 1) { sm += __shfl_down(sm, o); ssq += __shfl_down(ssq, o); }
    if ((t & 63) == 0) { red[t >> 6] = sm; red[4 + (t >> 6)] = ssq; }
    __syncthreads();
    const float S  = red[0] + red[1] + red[2] + red[3];
    const float SS = red[4] + red[5] + red[6] + red[7];
    const float mean = S * (1.f / 256.f);
    const float var  = SS * (1.f / 256.f) - mean * mean;
    const float rstd = rsqrtf(var + 1e-5f);
    p.ff_bf[(size_t)row * 256 + t] = f2bf((s - mean) * rstd * p.ln_ff_g[t] + p.ln_ff_b[t]);
}

// ============================ K7: MLP1 (relu -> bf16) =======================
// grid (4, 16): 64x64 tiles over C[256, 1024].
__global__ __launch_bounds__(256) void k_mlp1(Params p) {
    __shared__ unsigned short As[64 * 32], Bs[64 * 32];
    const int m0 = blockIdx.x * 64, n0 = blockIdx.y * 64;
    const int t = threadIdx.x, wave = t >> 6, lane = t & 63;
    const int lr = lane & 15, lq = lane >> 4;
    f32x4 acc[4] = {};
    const int sr = t >> 2, sl = t & 3, gk = sl * 8;
    const int wsl = (sl ^ ((sr >> 1) & 3)) * 8;
    for (int k0 = 0; k0 < 256; k0 += 32) {
        __syncthreads();
        uint4 a0 = *(const uint4*)(p.ff_bf + (size_t)(m0 + sr) * 256 + k0 + gk);
        uint4 b0 = *(const uint4*)(p.w1_bf + (size_t)(n0 + sr) * 256 + k0 + gk);
        *(uint4*)(As + sr * 32 + wsl) = a0;
        *(uint4*)(Bs + sr * 32 + wsl) = b0;
        __syncthreads();
        const int ra = wave * 16 + lr;
        bf16x8 af = *(const bf16x8*)(As + ra * 32 + ((lq ^ ((ra >> 1) & 3)) * 8));
        #pragma unroll
        for (int j = 0; j < 4; ++j) {
            const int rb = j * 16 + lr;
            bf16x8 bv = *(const bf16x8*)(Bs + rb * 32 + ((lq ^ ((rb >> 1) & 3)) * 8));
            acc[j] = MFMA16(af, bv, acc[j]);
        }
    }
    #pragma unroll
    for (int j = 0; j < 4; ++j) {
        const int col = n0 + j * 16 + lr;
        const float bb = p.b1[col];
        #pragma unroll
        for (int r = 0; r < 4; ++r) {
            const int row = m0 + wave * 16 + lq * 4 + r;
            p.h1_bf[(size_t)row * 1024 + col] = f2bf(fmaxf(acc[j][r] + bb, 0.f));
        }
    }
}

// ============================ K8: MLP2 partials =============================
// grid (16, 4): strip bx (16 rows) x K-chunk by (256 of 1024). Partial f32 out.
__global__ __launch_bounds__(256) void k_out(Params p) {
    __shared__ unsigned short a_s[16][264];
    const int t = threadIdx.x;
    const int r0 = blockIdx.x * 16, kb = blockIdx.y * 256;
    const int row16 = t >> 4, sub = t & 15;
    {   // stage A: h1 strip, 16 rows x 256 k of this chunk
        const unsigned short* src = p.h1_bf + (size_t)(r0 + row16) * 1024 + kb + sub * 16;
        *(uint4*)&a_s[row16][sub * 16]     = *(const uint4*)(src);
        *(uint4*)&a_s[row16][sub * 16 + 8] = *(const uint4*)(src + 8);
    }
    __syncthreads();
    const int w = t >> 6, lane = t & 63;
    const int lr = lane & 15, lq = lane >> 4;
    f32x4 acc[4] = {};
    for (int k0 = 0; k0 < 256; k0 += 32) {
        bf16x8 a = *(const bf16x8*)&a_s[lr][k0 + lq * 8];
        #pragma unroll
        for (int j = 0; j < 4; ++j) {
            bf16x8 bv = *(const bf16x8*)(p.w2_bf + (size_t)(w * 64 + j * 16 + lr) * 1024 + kb + k0 + lq * 8);
            acc[j] = MFMA16(a, bv, acc[j]);
        }
    }
    #pragma unroll
    for (int j = 0; j < 4; ++j)
        #pragma unroll
        for (int r = 0; r < 4; ++r)
            p.opart[((size_t)blockIdx.y * 256 + r0 + lq * 4 + r) * 256 + w * 64 + j * 16 + lr] = acc[j][r];
}

// ============================ K9: reduce + residual + LN + q ================
template<int LAST>
__global__ __launch_bounds__(256) void k_lnq(Params p) {
    __shared__ unsigned short u[16][264];
    const int t = threadIdx.x;
    const int r0 = blockIdx.x * 16;
    const int row16 = t >> 4, sub = t & 15;
    float vals[16]; float s_ = 0.f, ss = 0.f;
    #pragma unroll
    for (int k = 0; k < 16; ++k) {
        const int c = sub * 16 + k;
        const size_t ridx = (size_t)(r0 + row16) * 256 + c;
        float v = p.opart[(size_t)(r0 + row16) * 256 + c]
                + p.opart[((size_t)256 + r0 + row16) * 256 + c]
                + p.opart[((size_t)512 + r0 + row16) * 256 + c]
                + p.opart[((size_t)768 + r0 + row16) * 256 + c]
                + p.b2[c] + p.slots[ridx];
        p.slots[ridx] = v;
        if (LAST) p.out[ridx] = v;
        vals[k] = v; s_ += v; ss += v * v;
    }
    if (LAST) return;
    #pragma unroll
    for (int m = 1; m < 16; m <<= 1) { s_ += __shfl_xor(s_, m); ss += __shfl_xor(ss, m); }
    const float mean = s_ * (1.f / 256.f);
    const float var  = ss * (1.f / 256.f) - mean * mean;
    const float rstd = rsqrtf(var + 1e-5f);
    #pragma unroll
    for (int k = 0; k < 16; ++k) {
        const int c = sub * 16 + k;
        u[row16][c] = f2bf((vals[k] - mean) * rstd * p.ln_s_g[c] + p.ln_s_b[c]);
    }
    __syncthreads();
    qgemm(p, u, r0);
}

// ---------------------------------------------------------------------------
extern "C" void kernel_launch(void* const* d_in, const int* in_sizes, int n_in,
                              void* d_out, int out_size, void* d_ws, size_t ws_size,
                              hipStream_t stream)
{
    (void)in_sizes; (void)n_in; (void)out_size; (void)ws_size;

    Params prm;
    prm.inputs  = (const float*)d_in[0];
    prm.noise   = (const float*)d_in[1];
    prm.mu      = (const float*)d_in[2];
    prm.ls      = (const float*)d_in[3];
    prm.Wq      = (const float*)d_in[4];
    prm.Wk      = (const float*)d_in[5];
    prm.Wv      = (const float*)d_in[6];
    prm.wih     = (const float*)d_in[7];
    prm.whh     = (const float*)d_in[8];
    prm.bih     = (const float*)d_in[9];
    prm.bhh     = (const float*)d_in[10];
    prm.w1      = (const float*)d_in[11];
    prm.b1      = (const float*)d_in[12];
    prm.w2      = (const float*)d_in[13];
    prm.b2      = (const float*)d_in[14];
    prm.ln_in_g = (const float*)d_in[15];
    prm.ln_in_b = (const float*)d_in[16];
    prm.ln_s_g  = (const float*)d_in[17];
    prm.ln_s_b  = (const float*)d_in[18];
    prm.ln_ff_g = (const float*)d_in[19];
    prm.ln_ff_b = (const float*)d_in[20];
    prm.out     = (float*)d_out;

    char* ptr = (char*)d_ws;
    auto alloc = [&](size_t bytes) -> char* {
        char* r = ptr; ptr += (bytes + 255) & ~(size_t)255; return r;
    };
    prm.x_bf   = (unsigned short*)alloc((size_t)32768 * 256 * 2);
    prm.kv_bf  = (unsigned short*)alloc((size_t)32768 * 512 * 2);
    prm.kvW_bf = (unsigned short*)alloc(512 * 256 * 2);
    prm.Wq_bf  = (unsigned short*)alloc(256 * 256 * 2);
    prm.wih_bf = (unsigned short*)alloc(768 * 256 * 2);
    prm.whh_bf = (unsigned short*)alloc(768 * 256 * 2);
    prm.w1_bf  = (unsigned short*)alloc(1024 * 256 * 2);
    prm.w2_bf  = (unsigned short*)alloc(256 * 1024 * 2);
    prm.slots  = (float*)         alloc(256 * 256 * 4);
    prm.q      = (float*)         alloc(256 * 256 * 4);
    prm.upart  = (float*)         alloc((size_t)32 * 16 * 8 * 256 * 4);
    prm.rspart = (float*)         alloc(32 * 16 * 8 * 4);
    prm.u_bf   = (unsigned short*)alloc(256 * 256 * 2);
    prm.h_bf   = (unsigned short*)alloc(256 * 256 * 2);
    prm.gi     = (float*)         alloc(256 * 768 * 4);
    prm.gh     = (float*)         alloc(256 * 768 * 4);
    prm.ff_bf  = (unsigned short*)alloc(256 * 256 * 2);
    prm.h1_bf  = (unsigned short*)alloc(256 * 1024 * 2);
    prm.opart  = (float*)         alloc((size_t)4 * 256 * 256 * 4);

    k_prep<<<4608, 256, 0, stream>>>(prm);
    k_kv  <<<1040, 256, 0, stream>>>(prm);
    for (int it = 0; it < 3; ++it) {
        k_attn <<<512, 256, 0, stream>>>(prm);
        k_u2b  <<<256, 256, 0, stream>>>(prm);
        k_gates<<<dim3(4, 24), 256, 0, stream>>>(prm);
        k_gruln<<<256, 256, 0, stream>>>(prm);
        k_mlp1 <<<dim3(4, 16), 256, 0, stream>>>(prm);
        k_out  <<<dim3(16, 4), 256, 0, stream>>>(prm);
        if (it < 2) k_lnq<0><<<16, 256, 0, stream>>>(prm);
        else        k_lnq<1><<<16, 256, 0, stream>>>(prm);
    }
}